// Round 1
// baseline (273.105 us; speedup 1.0000x reference)
//
#include <hip/hip_runtime.h>

// Problem constants (match reference setup_inputs)
#define BB   16384
#define NJ   14
#define COLS 14
// h elements = B*NJ*COL*COL = 44,957,696 (divisible by 4)
#define N_H   (BB * NJ * COLS * COLS)
#define N_H4  (N_H / 4)
#define BNJ   (BB * NJ)

__global__ __launch_bounds__(256) void mse2_fused_kernel(
    const float* __restrict__ h,
    const float* __restrict__ t,
    const int*   __restrict__ v,
    float* __restrict__ out)
{
    const int tid      = blockIdx.x * blockDim.x + threadIdx.x;
    const int nthreads = gridDim.x * blockDim.x;

    float acc = 0.0f;

    // ---- sum(h^2), vectorized float4 grid-stride ----
    const float4* __restrict__ h4 = (const float4*)h;
    for (int i = tid; i < N_H4; i += nthreads) {
        float4 x = h4[i];
        acc = fmaf(x.x, x.x, acc);
        acc = fmaf(x.y, x.y, acc);
        acc = fmaf(x.z, x.z, acc);
        acc = fmaf(x.w, x.w, acc);
    }

    // ---- correction: for each visible joint, (h-1)^2 - h^2 = 1 - 2h ----
    for (int i = tid; i < BNJ; i += nthreads) {
        if (v[i] == 1) {
            float tx = t[2 * i];
            float ty = t[2 * i + 1];
            int xi = (int)(tx * (float)COLS);   // trunc toward zero; t >= 0
            int yi = (int)(ty * (float)COLS);
            xi = min(max(xi, 0), COLS - 1);
            yi = min(max(yi, 0), COLS - 1);
            float hv = h[(size_t)i * (COLS * COLS) + xi * COLS + yi];
            acc += 1.0f - 2.0f * hv;
        }
    }

    // ---- wave-64 shuffle reduction ----
    for (int off = 32; off > 0; off >>= 1)
        acc += __shfl_down(acc, off, 64);

    __shared__ float smem[4];   // 256 threads = 4 waves
    const int lane = threadIdx.x & 63;
    const int wave = threadIdx.x >> 6;
    if (lane == 0) smem[wave] = acc;
    __syncthreads();

    if (threadIdx.x == 0) {
        float s = smem[0] + smem[1] + smem[2] + smem[3];
        // scale by 2/N so the atomic target ends at the final answer
        const float inv_n = 2.0f / (float)N_H;   // N_H = 2^17 * 343, exact in fp32
        atomicAdd(out, s * inv_n);
    }
}

extern "C" void kernel_launch(void* const* d_in, const int* in_sizes, int n_in,
                              void* d_out, int out_size, void* d_ws, size_t ws_size,
                              hipStream_t stream) {
    // inputs: o (unused), h, t, v
    const float* h = (const float*)d_in[1];
    const float* t = (const float*)d_in[2];
    const int*   v = (const int*)d_in[3];
    float* out = (float*)d_out;

    // d_out is poisoned to 0xAA before every timed call — zero it.
    hipMemsetAsync(d_out, 0, sizeof(float), stream);

    const int block = 256;
    const int grid  = 2048;   // 256 CUs x ~8 blocks: enough waves to hide HBM latency
    mse2_fused_kernel<<<grid, block, 0, stream>>>(h, t, v, out);
}

// Round 3
// 265.329 us; speedup vs baseline: 1.0293x; 1.0293x over previous
//
#include <hip/hip_runtime.h>

// Problem constants (match reference setup_inputs)
#define BB   16384
#define NJ   14
#define COLS 14
#define N_H   (BB * NJ * COLS * COLS)   // 44,957,696 floats
#define N_H4  (N_H / 4)                 // 11,239,424 float4
#define BNJ   (BB * NJ)                 // 229,376 joints

// Native clang vector type — __builtin_nontemporal_load needs this, not HIP's float4.
typedef float vfloat4 __attribute__((ext_vector_type(4)));

// Launch geometry baked in so the main loop has a compile-time trip count.
constexpr int BLOCK = 256;
constexpr int GRID  = 2048;
constexpr int NT    = GRID * BLOCK;            // 524,288 threads
constexpr int FULL_ITERS = N_H4 / NT;          // 21
constexpr int REM        = N_H4 - FULL_ITERS * NT; // 229,376

__global__ __launch_bounds__(BLOCK) void mse2_fused_kernel(
    const float* __restrict__ h,
    const float* __restrict__ t,
    const int*   __restrict__ v,
    float* __restrict__ out)
{
    const int tid = blockIdx.x * BLOCK + threadIdx.x;

    float a0 = 0.0f, a1 = 0.0f, a2 = 0.0f, a3 = 0.0f;

    // ---- sum(h^2): compile-time trip count, 7 loads in flight, nt (stream) ----
    const vfloat4* __restrict__ h4 = (const vfloat4*)h;
#pragma unroll 7
    for (int k = 0; k < FULL_ITERS; ++k) {
        vfloat4 x = __builtin_nontemporal_load(&h4[tid + k * NT]);
        a0 = fmaf(x.x, x.x, a0);
        a1 = fmaf(x.y, x.y, a1);
        a2 = fmaf(x.z, x.z, a2);
        a3 = fmaf(x.w, x.w, a3);
    }
    // remainder: exactly REM threads take one more float4
    if (tid < REM) {
        vfloat4 x = __builtin_nontemporal_load(&h4[tid + FULL_ITERS * NT]);
        a0 = fmaf(x.x, x.x, a0);
        a1 = fmaf(x.y, x.y, a1);
        a2 = fmaf(x.z, x.z, a2);
        a3 = fmaf(x.w, x.w, a3);
    }
    float acc = (a0 + a1) + (a2 + a3);

    // ---- correction: visible joint -> (h-1)^2 - h^2 = 1 - 2h. One per thread. ----
    if (tid < BNJ) {
        if (v[tid] == 1) {
            float tx = t[2 * tid];
            float ty = t[2 * tid + 1];
            int xi = (int)(tx * (float)COLS);   // trunc; t >= 0
            int yi = (int)(ty * (float)COLS);
            xi = min(max(xi, 0), COLS - 1);
            yi = min(max(yi, 0), COLS - 1);
            float hv = h[(size_t)tid * (COLS * COLS) + xi * COLS + yi];
            acc += 1.0f - 2.0f * hv;
        }
    }

    // ---- wave-64 shuffle reduction ----
    for (int off = 32; off > 0; off >>= 1)
        acc += __shfl_down(acc, off, 64);

    __shared__ float smem[BLOCK / 64];
    const int lane = threadIdx.x & 63;
    const int wave = threadIdx.x >> 6;
    if (lane == 0) smem[wave] = acc;
    __syncthreads();

    if (threadIdx.x == 0) {
        float s = (smem[0] + smem[1]) + (smem[2] + smem[3]);
        const float inv_n = 2.0f / (float)N_H;   // exact in fp32
        atomicAdd(out, s * inv_n);
    }
}

extern "C" void kernel_launch(void* const* d_in, const int* in_sizes, int n_in,
                              void* d_out, int out_size, void* d_ws, size_t ws_size,
                              hipStream_t stream) {
    // inputs: o (unused), h, t, v
    const float* h = (const float*)d_in[1];
    const float* t = (const float*)d_in[2];
    const int*   v = (const int*)d_in[3];
    float* out = (float*)d_out;

    // d_out is poisoned to 0xAA before every timed call — zero it.
    (void)hipMemsetAsync(d_out, 0, sizeof(float), stream);

    mse2_fused_kernel<<<GRID, BLOCK, 0, stream>>>(h, t, v, out);
}